// Round 17
// baseline (2780.125 us; speedup 1.0000x reference)
//
#include <hip/hip_runtime.h>

typedef __attribute__((ext_vector_type(8))) short short8;
typedef __attribute__((ext_vector_type(4))) float f32x4;
typedef __attribute__((ext_vector_type(4))) unsigned u32x4;

__device__ __forceinline__ unsigned short f2bf(float f) {
  unsigned int u = __float_as_uint(f);
  u = (u + 0x7fffu + ((u >> 16) & 1u)) >> 16;
  return (unsigned short)u;
}

__device__ __forceinline__ void xp_store(float* p, float v) { *p = v; }
__device__ __forceinline__ void xp_store(unsigned short* p, float v) { *p = f2bf(v); }
__device__ __forceinline__ float xp_ld(const float* p) { return *p; }
__device__ __forceinline__ float xp_ld(const unsigned short* p) {
  return __uint_as_float(((unsigned int)*p) << 16);
}

// ---------------- prep: pack W_x (f32 -> bf16 pairs) ----------------
__global__ void prep_wx(const float* __restrict__ W, unsigned int* __restrict__ Wx2) {
  int i = blockIdx.x * 256 + threadIdx.x;  // 1024*128 dwords
  int g = i >> 7, kk = i & 127;
  float lo = W[(size_t)g * 512 + 256 + 2 * kk];
  float hi = W[(size_t)g * 512 + 256 + 2 * kk + 1];
  Wx2[i] = (unsigned int)f2bf(lo) | ((unsigned int)f2bf(hi) << 16);
}

// ---- prep W_h into MFMA B-fragments.
// Fragment f = (w*8+n)*8 + kt (w=wave, n=acc index, kt=K-tile). Lane l holds
// B[row=g][k]: g = 256*(n>>1) + 32*w + 16*(n&1) + (l&15), k = kt*32 + (l>>4)*8 + j.
// (Same B-fragment convention as the verified gemm_xp kernel.)
__global__ void prep_whB(const float* __restrict__ W, unsigned* __restrict__ WhB) {
  int i = blockIdx.x * 256 + threadIdx.x;  // 131072 dwords
  int f = i >> 8, lane = (i >> 2) & 63, jd = i & 3;
  int w = f >> 6, n = (f >> 3) & 7, kt = f & 7;
  int g = 256 * (n >> 1) + 32 * w + 16 * (n & 1) + (lane & 15);
  int k = kt * 32 + ((lane >> 4) << 3) + 2 * jd;
  float lo = W[(size_t)g * 512 + k];
  float hi = W[(size_t)g * 512 + k + 1];
  WhB[i] = (unsigned)f2bf(lo) | ((unsigned)f2bf(hi) << 16);
}

// ---------------- GEMM: xp[m][g] = sum_k x[m][k] * Wx[g][k] + b[g] ----------------
template <typename XPT>
__global__ __launch_bounds__(256, 4) void gemm_xp(const float* __restrict__ x,
                                                  const unsigned int* __restrict__ Wx2,
                                                  const float* __restrict__ bias,
                                                  XPT* __restrict__ xp) {
  __shared__ unsigned short As[128][40];
  __shared__ unsigned short Bs[128][40];
  const int m0 = blockIdx.y * 128, n0 = blockIdx.x * 128;
  const int tid = threadIdx.x, lane = tid & 63, w = tid >> 6;
  const int wr = w >> 1, wc = w & 1;
  const int r16 = lane & 15, kq = lane >> 4;
  f32x4 acc[4][4];
#pragma unroll
  for (int m = 0; m < 4; m++)
#pragma unroll
    for (int n = 0; n < 4; n++)
#pragma unroll
      for (int j = 0; j < 4; j++) acc[m][n][j] = 0.f;

  for (int kb = 0; kb < 256; kb += 32) {
    __syncthreads();
#pragma unroll
    for (int i = 0; i < 4; i++) {
      int idx = tid + i * 256;
      int row = idx >> 3, c4 = idx & 7;
      float4 v = *(const float4*)(x + (size_t)(m0 + row) * 256 + kb + c4 * 4);
      ushort4 s;
      s.x = f2bf(v.x); s.y = f2bf(v.y); s.z = f2bf(v.z); s.w = f2bf(v.w);
      *(ushort4*)&As[row][c4 * 4] = s;
    }
#pragma unroll
    for (int i = 0; i < 2; i++) {
      int idx = tid + i * 256;
      int row = idx >> 2, c = idx & 3;
      uint4 v = *(const uint4*)(Wx2 + (size_t)(n0 + row) * 128 + (kb >> 1) + c * 4);
      *(uint4*)&Bs[row][c * 8] = v;
    }
    __syncthreads();
    short8 a[4], bb[4];
#pragma unroll
    for (int m = 0; m < 4; m++)
      a[m] = *(const short8*)&As[wr * 64 + m * 16 + r16][kq * 8];
#pragma unroll
    for (int n = 0; n < 4; n++)
      bb[n] = *(const short8*)&Bs[wc * 64 + n * 16 + r16][kq * 8];
#pragma unroll
    for (int m = 0; m < 4; m++)
#pragma unroll
      for (int n = 0; n < 4; n++)
        acc[m][n] = __builtin_amdgcn_mfma_f32_16x16x32_bf16(a[m], bb[n], acc[m][n], 0, 0, 0);
  }
#pragma unroll
  for (int n = 0; n < 4; n++) {
    int gn = n0 + wc * 64 + n * 16 + r16;
    float bi = bias[gn];
#pragma unroll
    for (int m = 0; m < 4; m++) {
      int gm = m0 + wr * 64 + m * 16 + kq * 4;
#pragma unroll
      for (int j = 0; j < 4; j++) {
        xp_store(&xp[(size_t)(gm + j) * 1024 + gn], acc[m][n][j] + bi);
      }
    }
  }
}

// ---------------- recurrence: MFMA GEMV, one batch per CU --------------------------
// R8-R16 LESSON: all nulls are explained by v_dot2_f32_bf16 being ~quarter-rate:
// 2048 dot2 wave-insts/CU/step x 8cy / 4 SIMDs = 4096 cy = the whole observed step.
// R17 moves the GEMV to the matrix pipe: 512 MFMA(16x16x32 bf16, ~5cy)/CU/step / 8
// waves = 64/wave -> ~640 cy/SIMD. A-fragment = h BROADCAST to all 16 M-rows (no
// masking; every D-row equals the true GEMV, so every lane holds the preact for col
// lane&15). B-fragments: wave w, acc n covers gate 256*(n>>1), units 32w+16*(n&1)+c;
// kt=0..5 register-resident (192 dw, asm-volatile loads; AGPR placement proven safe
// in R16 -- verify FETCH stays ~xp-only), kt=6..7 streamed from 128KB LDS col-major.
// D: acc_n[0] gives lane c all four gates of units 32w+c / 32w+16+c -> in-register
// LSTM (redundant x4 across lane>>4 groups, deterministic), no reduce, no gate
// exchange, ONE raw barrier per step. h: bf16[2][256] LDS double buffer.
template <typename XPT>
__global__ __attribute__((amdgpu_flat_work_group_size(512, 512),
                          amdgpu_waves_per_eu(2, 2)))
void lstm_rec(const unsigned* __restrict__ WhB,
              const XPT* __restrict__ xp,
              float* __restrict__ out) {
  __shared__ u32x4 wotB[16 * 512];          // 131072 B: streamed B frags kt=6,7
  __shared__ unsigned short hl[2][256];     // 1 KB: h bf16, double-buffered

  const int tid = threadIdx.x;
  const int b = blockIdx.x;
  const int lane = tid & 63, w = tid >> 6;
  const int c = lane & 15;
  const int brow0 = b << 10;

  // ---- resident B fragments: n=0..7, kt=0..5 (48 named short8 = 192 dwords)
  short8 B00, B01, B02, B03, B04, B05, B10, B11, B12, B13, B14, B15;
  short8 B20, B21, B22, B23, B24, B25, B30, B31, B32, B33, B34, B35;
  short8 B40, B41, B42, B43, B44, B45, B50, B51, B52, B53, B54, B55;
  short8 B60, B61, B62, B63, B64, B65, B70, B71, B72, B73, B74, B75;
#define LOADB4(P, R0, R1, R2, R3)                                     \
  asm volatile("global_load_dwordx4 %0, %4, off\n\t"                  \
               "global_load_dwordx4 %1, %4, off offset:1024\n\t"      \
               "global_load_dwordx4 %2, %4, off offset:2048\n\t"      \
               "global_load_dwordx4 %3, %4, off offset:3072"          \
               : "=&v"(R0), "=&v"(R1), "=&v"(R2), "=&v"(R3)           \
               : "v"(P) : "memory")
#define LOADB2(P, R0, R1)                                             \
  asm volatile("global_load_dwordx4 %0, %2, off\n\t"                  \
               "global_load_dwordx4 %1, %2, off offset:1024"          \
               : "=&v"(R0), "=&v"(R1) : "v"(P) : "memory")
#define LOADN(N, RA, RB, RC, RD, RE, RF)                              \
  {                                                                   \
    const unsigned* bp = WhB + ((((w << 3) + N) << 11)) + (lane << 2);\
    LOADB4(bp, RA, RB, RC, RD);                                       \
    LOADB2(bp + 1024, RE, RF);                                        \
  }
  LOADN(0, B00, B01, B02, B03, B04, B05)
  LOADN(1, B10, B11, B12, B13, B14, B15)
  LOADN(2, B20, B21, B22, B23, B24, B25)
  LOADN(3, B30, B31, B32, B33, B34, B35)
  LOADN(4, B40, B41, B42, B43, B44, B45)
  LOADN(5, B50, B51, B52, B53, B54, B55)
  LOADN(6, B60, B61, B62, B63, B64, B65)
  LOADN(7, B70, B71, B72, B73, B74, B75)
#undef LOADN
#undef LOADB4
#undef LOADB2
  asm volatile("s_waitcnt vmcnt(0)" ::: "memory");

  // ---- streamed B fragments kt=6,7 -> LDS (slot s = n*2 + (kt-6))
#pragma unroll
  for (int s = 0; s < 16; s++) {
    int n = s >> 1, kt = 6 + (s & 1);
    wotB[(s << 9) + tid] =
        *(const u32x4*)(WhB + ((((w << 3) + n) << 3) + kt) * 256 + (lane << 2));
  }

  if (tid < 256) { hl[0][tid] = 0; hl[1][tid] = 0; }
  float c0 = 0.f, c1 = 0.f;
  float* outp = out + ((size_t)brow0 << 8);
  __syncthreads();

#define BAR() asm volatile("s_waitcnt lgkmcnt(0)\n\ts_barrier" ::: "memory")
#define MF(A, Bf, C) __builtin_amdgcn_mfma_f32_16x16x32_bf16(A, Bf, C, 0, 0, 0)
#define LSTM1(AF, AI, AG, AO, X0, X1, X2, X3, CC, HOUT)             \
  {                                                                 \
    float gf = AF + X0, gi = AI + X1, gg = AG + X2, go = AO + X3;   \
    float f = 1.f / (1.f + __expf(-gf));                            \
    float ii = 1.f / (1.f + __expf(-gi));                           \
    float eg = __expf(2.f * gg);                                    \
    float gtv = (eg - 1.f) / (eg + 1.f);                            \
    float o = 1.f / (1.f + __expf(-go));                            \
    CC = f * CC + ii * gtv;                                         \
    float ec = __expf(2.f * CC);                                    \
    float tc = (ec - 1.f) / (ec + 1.f);                             \
    HOUT = o * tc;                                                  \
  }

#define STEP(T, RS, WS)                                                                \
  {                                                                                    \
    const int t = (T);                                                                 \
    /* xp for this step: direct global loads, consumed after the MFMA block */         \
    const XPT* xr = xp + ((size_t)(brow0 + t) << 10);                                  \
    const int u0 = 32 * w + c;                                                         \
    float xv0 = xp_ld(xr + u0),        xv1 = xp_ld(xr + u0 + 16);                      \
    float xv2 = xp_ld(xr + 256 + u0),  xv3 = xp_ld(xr + 256 + u0 + 16);                \
    float xv4 = xp_ld(xr + 512 + u0),  xv5 = xp_ld(xr + 512 + u0 + 16);                \
    float xv6 = xp_ld(xr + 768 + u0),  xv7 = xp_ld(xr + 768 + u0 + 16);                \
    /* A fragments: broadcast h slice (all M-rows identical) */                        \
    const short8* hfr = (const short8*)&hl[RS][0];                                     \
    const int q = lane >> 4;                                                           \
    const f32x4 Z = {0.f, 0.f, 0.f, 0.f};                                              \
    short8 a = hfr[q];                                                                 \
    f32x4 p0 = MF(a, B00, Z), p1 = MF(a, B10, Z), p2 = MF(a, B20, Z),                  \
          p3 = MF(a, B30, Z), p4 = MF(a, B40, Z), p5 = MF(a, B50, Z),                  \
          p6 = MF(a, B60, Z), p7 = MF(a, B70, Z);                                      \
    a = hfr[4 + q];                                                                    \
    p0 = MF(a, B01, p0); p1 = MF(a, B11, p1); p2 = MF(a, B21, p2);                     \
    p3 = MF(a, B31, p3); p4 = MF(a, B41, p4); p5 = MF(a, B51, p5);                     \
    p6 = MF(a, B61, p6); p7 = MF(a, B71, p7);                                          \
    a = hfr[8 + q];                                                                    \
    p0 = MF(a, B02, p0); p1 = MF(a, B12, p1); p2 = MF(a, B22, p2);                     \
    p3 = MF(a, B32, p3); p4 = MF(a, B42, p4); p5 = MF(a, B52, p5);                     \
    p6 = MF(a, B62, p6); p7 = MF(a, B72, p7);                                          \
    a = hfr[12 + q];                                                                   \
    p0 = MF(a, B03, p0); p1 = MF(a, B13, p1); p2 = MF(a, B23, p2);                     \
    p3 = MF(a, B33, p3); p4 = MF(a, B43, p4); p5 = MF(a, B53, p5);                     \
    p6 = MF(a, B63, p6); p7 = MF(a, B73, p7);                                          \
    a = hfr[16 + q];                                                                   \
    p0 = MF(a, B04, p0); p1 = MF(a, B14, p1); p2 = MF(a, B24, p2);                     \
    p3 = MF(a, B34, p3); p4 = MF(a, B44, p4); p5 = MF(a, B54, p5);                     \
    p6 = MF(a, B64, p6); p7 = MF(a, B74, p7);                                          \
    a = hfr[20 + q];                                                                   \
    p0 = MF(a, B05, p0); p1 = MF(a, B15, p1); p2 = MF(a, B25, p2);                     \
    p3 = MF(a, B35, p3); p4 = MF(a, B45, p4); p5 = MF(a, B55, p5);                     \
    p6 = MF(a, B65, p6); p7 = MF(a, B75, p7);                                          \
    /* streamed kt=6,7 from LDS */                                                     \
    a = hfr[24 + q];                                                                   \
    p0 = MF(a, *(const short8*)&wotB[(0 << 9) + tid], p0);                             \
    p1 = MF(a, *(const short8*)&wotB[(2 << 9) + tid], p1);                             \
    p2 = MF(a, *(const short8*)&wotB[(4 << 9) + tid], p2);                             \
    p3 = MF(a, *(const short8*)&wotB[(6 << 9) + tid], p3);                             \
    p4 = MF(a, *(const short8*)&wotB[(8 << 9) + tid], p4);                             \
    p5 = MF(a, *(const short8*)&wotB[(10 << 9) + tid], p5);                            \
    p6 = MF(a, *(const short8*)&wotB[(12 << 9) + tid], p6);                            \
    p7 = MF(a, *(const short8*)&wotB[(14 << 9) + tid], p7);                            \
    a = hfr[28 + q];                                                                   \
    p0 = MF(a, *(const short8*)&wotB[(1 << 9) + tid], p0);                             \
    p1 = MF(a, *(const short8*)&wotB[(3 << 9) + tid], p1);                             \
    p2 = MF(a, *(const short8*)&wotB[(5 << 9) + tid], p2);                             \
    p3 = MF(a, *(const short8*)&wotB[(7 << 9) + tid], p3);                             \
    p4 = MF(a, *(const short8*)&wotB[(9 << 9) + tid], p4);                             \
    p5 = MF(a, *(const short8*)&wotB[(11 << 9) + tid], p5);                            \
    p6 = MF(a, *(const short8*)&wotB[(13 << 9) + tid], p6);                            \
    p7 = MF(a, *(const short8*)&wotB[(15 << 9) + tid], p7);                            \
    /* lane c holds all four gates of units 32w+c (even n) and 32w+16+c (odd n) */     \
    float h0v, h1v;                                                                    \
    LSTM1(p0[0], p2[0], p4[0], p6[0], xv0, xv2, xv4, xv6, c0, h0v)                     \
    LSTM1(p1[0], p3[0], p5[0], p7[0], xv1, xv3, xv5, xv7, c1, h1v)                     \
    if (lane < 16) {                                                                   \
      hl[WS][u0] = f2bf(h0v);                                                          \
      hl[WS][u0 + 16] = f2bf(h1v);                                                     \
      __builtin_nontemporal_store(h0v, outp + ((size_t)t << 8) + u0);                  \
      __builtin_nontemporal_store(h1v, outp + ((size_t)t << 8) + u0 + 16);             \
      if (t == 1023) {                                                                 \
        out[16777216 + b * 256 + u0] = h0v;                                            \
        out[16777216 + b * 256 + u0 + 16] = h1v;                                       \
        out[16777216 + 16384 + b * 256 + u0] = c0;                                     \
        out[16777216 + 16384 + b * 256 + u0 + 16] = c1;                                \
      }                                                                                \
    }                                                                                  \
    BAR();                                                                             \
  }

  for (int t2 = 0; t2 < 1024; t2 += 2) {
    STEP(t2, 1, 0)      // t even: read h slot1, write slot0
    STEP(t2 + 1, 0, 1)  // t odd:  read h slot0, write slot1
  }
#undef STEP
#undef LSTM1
#undef MF
#undef BAR
}

extern "C" void kernel_launch(void* const* d_in, const int* in_sizes, int n_in,
                              void* d_out, int out_size, void* d_ws, size_t ws_size,
                              hipStream_t stream) {
  (void)in_sizes; (void)n_in; (void)out_size;
  const float* x = (const float*)d_in[0];
  const float* W = (const float*)d_in[1];
  const float* bias = (const float*)d_in[2];
  float* out = (float*)d_out;
  char* ws = (char*)d_ws;

  unsigned int* Wx2 = (unsigned int*)ws;              // 524288 B
  unsigned int* WhB = (unsigned int*)(ws + 524288);   // 524288 B (B-fragments)
  char* xpmem = ws + 1048576;

  const size_t need32 = 1048576 + (size_t)65536 * 1024 * 4;

  prep_wx<<<512, 256, 0, stream>>>(W, Wx2);
  prep_whB<<<512, 256, 0, stream>>>(W, WhB);

  if (ws_size >= need32) {
    gemm_xp<float><<<dim3(8, 512), 256, 0, stream>>>(x, Wx2, bias, (float*)xpmem);
    lstm_rec<float><<<64, 512, 0, stream>>>(WhB, (const float*)xpmem, out);
  } else {
    gemm_xp<unsigned short><<<dim3(8, 512), 256, 0, stream>>>(x, Wx2, bias,
                                                              (unsigned short*)xpmem);
    lstm_rec<unsigned short><<<64, 512, 0, stream>>>(WhB, (const unsigned short*)xpmem, out);
  }
}

// Round 19
// 2105.907 us; speedup vs baseline: 1.3202x; 1.3202x over previous
//
#include <hip/hip_runtime.h>

typedef __attribute__((ext_vector_type(8))) short short8;
typedef __attribute__((ext_vector_type(4))) float f32x4;
typedef __attribute__((ext_vector_type(4))) unsigned u32x4;

__device__ __forceinline__ unsigned short f2bf(float f) {
  unsigned int u = __float_as_uint(f);
  u = (u + 0x7fffu + ((u >> 16) & 1u)) >> 16;
  return (unsigned short)u;
}

__device__ __forceinline__ void xp_store(float* p, float v) { *p = v; }
__device__ __forceinline__ void xp_store(unsigned short* p, float v) { *p = f2bf(v); }
__device__ __forceinline__ float xp_ld(const float* p) { return *p; }
__device__ __forceinline__ float xp_ld(const unsigned short* p) {
  return __uint_as_float(((unsigned int)*p) << 16);
}

// quad reduce via DPP (VALU pipe, no DS): sum over the 4 lanes of each quad.
__device__ __forceinline__ float quad_sum(float a) {
  float t1 = __int_as_float(
      __builtin_amdgcn_update_dpp(0, __float_as_int(a), 177, 0xf, 0xf, true));
  a += t1;
  float t2 = __int_as_float(
      __builtin_amdgcn_update_dpp(0, __float_as_int(a), 78, 0xf, 0xf, true));
  return a + t2;
}

// ---------------- prep: pack W_x and W_h (f32 -> bf16 pairs) ----------------
__global__ void prep_wx(const float* __restrict__ W, unsigned int* __restrict__ Wx2) {
  int i = blockIdx.x * 256 + threadIdx.x;  // 1024*128 dwords
  int g = i >> 7, kk = i & 127;
  float lo = W[(size_t)g * 512 + 256 + 2 * kk];
  float hi = W[(size_t)g * 512 + 256 + 2 * kk + 1];
  Wx2[i] = (unsigned int)f2bf(lo) | ((unsigned int)f2bf(hi) << 16);
}

__global__ void prep_wh(const float* __restrict__ W, unsigned int* __restrict__ Wh2) {
  int i = blockIdx.x * 256 + threadIdx.x;  // 1024*128 dwords
  int r = i >> 7, kk = i & 127;
  float lo = W[(size_t)r * 512 + 2 * kk];
  float hi = W[(size_t)r * 512 + 2 * kk + 1];
  Wh2[i] = (unsigned int)f2bf(lo) | ((unsigned int)f2bf(hi) << 16);
}

// ---------------- GEMM: xp[m][g] = sum_k x[m][k] * Wx[g][k] + b[g] ----------------
template <typename XPT>
__global__ __launch_bounds__(256, 4) void gemm_xp(const float* __restrict__ x,
                                                  const unsigned int* __restrict__ Wx2,
                                                  const float* __restrict__ bias,
                                                  XPT* __restrict__ xp) {
  __shared__ unsigned short As[128][40];
  __shared__ unsigned short Bs[128][40];
  const int m0 = blockIdx.y * 128, n0 = blockIdx.x * 128;
  const int tid = threadIdx.x, lane = tid & 63, w = tid >> 6;
  const int wr = w >> 1, wc = w & 1;
  const int r16 = lane & 15, kq = lane >> 4;
  f32x4 acc[4][4];
#pragma unroll
  for (int m = 0; m < 4; m++)
#pragma unroll
    for (int n = 0; n < 4; n++)
#pragma unroll
      for (int j = 0; j < 4; j++) acc[m][n][j] = 0.f;

  for (int kb = 0; kb < 256; kb += 32) {
    __syncthreads();
#pragma unroll
    for (int i = 0; i < 4; i++) {
      int idx = tid + i * 256;
      int row = idx >> 3, c4 = idx & 7;
      float4 v = *(const float4*)(x + (size_t)(m0 + row) * 256 + kb + c4 * 4);
      ushort4 s;
      s.x = f2bf(v.x); s.y = f2bf(v.y); s.z = f2bf(v.z); s.w = f2bf(v.w);
      *(ushort4*)&As[row][c4 * 4] = s;
    }
#pragma unroll
    for (int i = 0; i < 2; i++) {
      int idx = tid + i * 256;
      int row = idx >> 2, c = idx & 3;
      uint4 v = *(const uint4*)(Wx2 + (size_t)(n0 + row) * 128 + (kb >> 1) + c * 4);
      *(uint4*)&Bs[row][c * 8] = v;
    }
    __syncthreads();
    short8 a[4], bb[4];
#pragma unroll
    for (int m = 0; m < 4; m++)
      a[m] = *(const short8*)&As[wr * 64 + m * 16 + r16][kq * 8];
#pragma unroll
    for (int n = 0; n < 4; n++)
      bb[n] = *(const short8*)&Bs[wc * 64 + n * 16 + r16][kq * 8];
#pragma unroll
    for (int m = 0; m < 4; m++)
#pragma unroll
      for (int n = 0; n < 4; n++)
        acc[m][n] = __builtin_amdgcn_mfma_f32_16x16x32_bf16(a[m], bb[n], acc[m][n], 0, 0, 0);
  }
#pragma unroll
  for (int n = 0; n < 4; n++) {
    int gn = n0 + wc * 64 + n * 16 + r16;
    float bi = bias[gn];
#pragma unroll
    for (int m = 0; m < 4; m++) {
      int gm = m0 + wr * 64 + m * 16 + kq * 4;
#pragma unroll
      for (int j = 0; j < 4; j++) {
        xp_store(&xp[(size_t)(gm + j) * 1024 + gn], acc[m][n][j] + bi);
      }
    }
  }
}

// ---------------- recurrence: 512 threads x 256-VGPR budget, 2 units/thread --------
// EXACT R16 revert (best verified: lstm_rec 2025us, absmax 0.0078). R18's o-cache +
// rotation removal broke correctness at ~224/256 pinned dwords -- at >85% pinned
// register occupancy, "minor" changes are not minor. Evidence ledger: conflicts
// (R10), DS count (R13/14), barrier drain (R14), pipelining (R15), wave count (R16),
// dot-pipe swap (R17) all addressed; every variant lands 2.0-2.7us/step with all
// counters near-idle -> per-step latency/convergence floor of this design space.
// Thread (v=tid>>2, p=tid&3) owns units (v, v+128) x 4 gates over k-slice
// [p*64,p*64+64). f,i,g rows of both units = 192 dw register-resident (asm-volatile
// loads, unified VGPR/AGPR); o-rows (64 dw) stream from LDS wot[16][512] col-major.
// h: bf16 pairs, 2 slots x 4 p-copies stride 136 (conflict-free); DPP quad reduce;
// raw barrier {lgkmcnt(0); s_barrier}; xp direct from global.
template <typename XPT>
__global__ __attribute__((amdgpu_flat_work_group_size(512, 512),
                          amdgpu_waves_per_eu(2, 2)))
void lstm_rec(const unsigned* __restrict__ Wh2,
              const XPT* __restrict__ xp,
              float* __restrict__ out) {
  __shared__ u32x4 wot[16 * 512];          // 131072B: o-rows of units v / v+128
  __shared__ unsigned hsh[2][4][136];      // 4352B: h bf16-pairs, 2 slots x 4 p-copies

  const int tid = threadIdx.x;
  const int b = blockIdx.x;
  const int v = tid >> 2, p = tid & 3;
  const int brow0 = b << 10;

  // ---- weight register loads: f,i,g rows of units v and v+128 (192 dwords)
  const unsigned* fA_p = Wh2 + (size_t)(v) * 128 + (p << 5);
  const unsigned* iA_p = Wh2 + (size_t)(256 + v) * 128 + (p << 5);
  const unsigned* gA_p = Wh2 + (size_t)(512 + v) * 128 + (p << 5);
  const unsigned* oA_p = Wh2 + (size_t)(768 + v) * 128 + (p << 5);
  const unsigned* fB_p = Wh2 + (size_t)(128 + v) * 128 + (p << 5);
  const unsigned* iB_p = Wh2 + (size_t)(384 + v) * 128 + (p << 5);
  const unsigned* gB_p = Wh2 + (size_t)(640 + v) * 128 + (p << 5);
  const unsigned* oB_p = Wh2 + (size_t)(896 + v) * 128 + (p << 5);
  u32x4 fA0, fA1, fA2, fA3, fA4, fA5, fA6, fA7;
  u32x4 iA0, iA1, iA2, iA3, iA4, iA5, iA6, iA7;
  u32x4 gA0, gA1, gA2, gA3, gA4, gA5, gA6, gA7;
  u32x4 fB0, fB1, fB2, fB3, fB4, fB5, fB6, fB7;
  u32x4 iB0, iB1, iB2, iB3, iB4, iB5, iB6, iB7;
  u32x4 gB0, gB1, gB2, gB3, gB4, gB5, gB6, gB7;
#define LOADROW8(P, R0, R1, R2, R3, R4, R5, R6, R7)                   \
  asm volatile("global_load_dwordx4 %0, %8, off\n\t"                  \
               "global_load_dwordx4 %1, %8, off offset:16\n\t"        \
               "global_load_dwordx4 %2, %8, off offset:32\n\t"        \
               "global_load_dwordx4 %3, %8, off offset:48\n\t"        \
               "global_load_dwordx4 %4, %8, off offset:64\n\t"        \
               "global_load_dwordx4 %5, %8, off offset:80\n\t"        \
               "global_load_dwordx4 %6, %8, off offset:96\n\t"        \
               "global_load_dwordx4 %7, %8, off offset:112"           \
               : "=&v"(R0), "=&v"(R1), "=&v"(R2), "=&v"(R3),          \
                 "=&v"(R4), "=&v"(R5), "=&v"(R6), "=&v"(R7)           \
               : "v"(P)                                               \
               : "memory")
  LOADROW8(fA_p, fA0, fA1, fA2, fA3, fA4, fA5, fA6, fA7);
  LOADROW8(iA_p, iA0, iA1, iA2, iA3, iA4, iA5, iA6, iA7);
  LOADROW8(gA_p, gA0, gA1, gA2, gA3, gA4, gA5, gA6, gA7);
  LOADROW8(fB_p, fB0, fB1, fB2, fB3, fB4, fB5, fB6, fB7);
  LOADROW8(iB_p, iB0, iB1, iB2, iB3, iB4, iB5, iB6, iB7);
  LOADROW8(gB_p, gB0, gB1, gB2, gB3, gB4, gB5, gB6, gB7);
#undef LOADROW8
  asm volatile("s_waitcnt vmcnt(0)" ::: "memory");

  // ---- o-rows -> LDS col-major: chunks E=0..7 unit A, E=8..15 unit B
#pragma unroll
  for (int E = 0; E < 8; E++) {
    wot[(E << 9) + tid] = *(const u32x4*)(oA_p + (E << 2));
    wot[((E + 8) << 9) + tid] = *(const u32x4*)(oB_p + (E << 2));
  }

  // ---- zero both h slots
  for (int i = tid; i < 2 * 4 * 136; i += 512) ((unsigned*)hsh)[i] = 0u;
  float c0 = 0.f, c1 = 0.f;
  float* outp = out + ((size_t)brow0 << 8);
  __syncthreads();  // one full barrier before the loop (covers LDS init)

#define BAR() asm volatile("s_waitcnt lgkmcnt(0)\n\ts_barrier" ::: "memory")
#define DOT2(ACC, WD, HD) \
  asm("v_dot2_f32_bf16 %0, %1, %2, %0" : "+v"(ACC) : "v"(WD), "v"(HD))
// dot one chunk: 2 units x 4 gates x 4 dwords = 32 dot2, all register operands
#define DOTC(FA, IA, GA, FB, IB, GB, OA, OB, HJ)                    \
  {                                                                 \
    DOT2(aF0, FA[0], (HJ)[0]); DOT2(aF0, FA[1], (HJ)[1]);           \
    DOT2(aF0, FA[2], (HJ)[2]); DOT2(aF0, FA[3], (HJ)[3]);           \
    DOT2(aI0, IA[0], (HJ)[0]); DOT2(aI0, IA[1], (HJ)[1]);           \
    DOT2(aI0, IA[2], (HJ)[2]); DOT2(aI0, IA[3], (HJ)[3]);           \
    DOT2(aG0, GA[0], (HJ)[0]); DOT2(aG0, GA[1], (HJ)[1]);           \
    DOT2(aG0, GA[2], (HJ)[2]); DOT2(aG0, GA[3], (HJ)[3]);           \
    DOT2(aO0, (OA)[0], (HJ)[0]); DOT2(aO0, (OA)[1], (HJ)[1]);       \
    DOT2(aO0, (OA)[2], (HJ)[2]); DOT2(aO0, (OA)[3], (HJ)[3]);       \
    DOT2(aF1, FB[0], (HJ)[0]); DOT2(aF1, FB[1], (HJ)[1]);           \
    DOT2(aF1, FB[2], (HJ)[2]); DOT2(aF1, FB[3], (HJ)[3]);           \
    DOT2(aI1, IB[0], (HJ)[0]); DOT2(aI1, IB[1], (HJ)[1]);           \
    DOT2(aI1, IB[2], (HJ)[2]); DOT2(aI1, IB[3], (HJ)[3]);           \
    DOT2(aG1, GB[0], (HJ)[0]); DOT2(aG1, GB[1], (HJ)[1]);           \
    DOT2(aG1, GB[2], (HJ)[2]); DOT2(aG1, GB[3], (HJ)[3]);           \
    DOT2(aO1, (OB)[0], (HJ)[0]); DOT2(aO1, (OB)[1], (HJ)[1]);       \
    DOT2(aO1, (OB)[2], (HJ)[2]); DOT2(aO1, (OB)[3], (HJ)[3]);       \
  }
#define HJC(HRX, J) (*(const u32x4*)&hsh[HRX][p][(p << 5) + ((J) << 2)])

#define LSTM1(AF, AI, AG, AO, X0, X1, X2, X3, CC, HOUT)             \
  {                                                                 \
    float gf = AF + X0, gi = AI + X1, gg = AG + X2, go = AO + X3;   \
    float f = 1.f / (1.f + __expf(-gf));                            \
    float ii = 1.f / (1.f + __expf(-gi));                           \
    float eg = __expf(2.f * gg);                                    \
    float gtv = (eg - 1.f) / (eg + 1.f);                            \
    float o = 1.f / (1.f + __expf(-go));                            \
    CC = f * CC + ii * gtv;                                         \
    float ec = __expf(2.f * CC);                                    \
    float tc = (ec - 1.f) / (ec + 1.f);                             \
    HOUT = o * tc;                                                  \
  }

#define STEP(T, HR, HW)                                                                \
  {                                                                                    \
    const int t = (T);                                                                 \
    /* xp for THIS step: direct global loads (VMEM pipe, consumed at gate add) */      \
    const XPT* xr = xp + ((size_t)(brow0 + t) << 10);                                  \
    float xv0 = xp_ld(xr + v),        xv1 = xp_ld(xr + 256 + v);                       \
    float xv2 = xp_ld(xr + 512 + v),  xv3 = xp_ld(xr + 768 + v);                       \
    float xw0 = xp_ld(xr + 128 + v),  xw1 = xp_ld(xr + 384 + v);                       \
    float xw2 = xp_ld(xr + 640 + v),  xw3 = xp_ld(xr + 896 + v);                       \
    /* depth-2 pipeline over chunks */                                                 \
    u32x4 hX = HJC(HR, 0), oAX = wot[(0 << 9) + tid], oBX = wot[(8 << 9) + tid];       \
    u32x4 hY = HJC(HR, 1), oAY = wot[(1 << 9) + tid], oBY = wot[(9 << 9) + tid];       \
    float aF0 = 0.f, aI0 = 0.f, aG0 = 0.f, aO0 = 0.f;                                  \
    float aF1 = 0.f, aI1 = 0.f, aG1 = 0.f, aO1 = 0.f;                                  \
    DOTC(fA0, iA0, gA0, fB0, iB0, gB0, oAX, oBX, hX)                                   \
    hX = HJC(HR, 2); oAX = wot[(2 << 9) + tid]; oBX = wot[(10 << 9) + tid];            \
    DOTC(fA1, iA1, gA1, fB1, iB1, gB1, oAY, oBY, hY)                                   \
    hY = HJC(HR, 3); oAY = wot[(3 << 9) + tid]; oBY = wot[(11 << 9) + tid];            \
    DOTC(fA2, iA2, gA2, fB2, iB2, gB2, oAX, oBX, hX)                                   \
    hX = HJC(HR, 4); oAX = wot[(4 << 9) + tid]; oBX = wot[(12 << 9) + tid];            \
    DOTC(fA3, iA3, gA3, fB3, iB3, gB3, oAY, oBY, hY)                                   \
    hY = HJC(HR, 5); oAY = wot[(5 << 9) + tid]; oBY = wot[(13 << 9) + tid];            \
    DOTC(fA4, iA4, gA4, fB4, iB4, gB4, oAX, oBX, hX)                                   \
    hX = HJC(HR, 6); oAX = wot[(6 << 9) + tid]; oBX = wot[(14 << 9) + tid];            \
    DOTC(fA5, iA5, gA5, fB5, iB5, gB5, oAY, oBY, hY)                                   \
    hY = HJC(HR, 7); oAY = wot[(7 << 9) + tid]; oBY = wot[(15 << 9) + tid];            \
    DOTC(fA6, iA6, gA6, fB6, iB6, gB6, oAX, oBX, hX)                                   \
    DOTC(fA7, iA7, gA7, fB7, iB7, gB7, oAY, oBY, hY)                                   \
    /* reduce over the 4 p-lanes: DPP quad_perm adds (VALU pipe, no DS) */             \
    aF0 = quad_sum(aF0); aI0 = quad_sum(aI0); aG0 = quad_sum(aG0); aO0 = quad_sum(aO0);\
    aF1 = quad_sum(aF1); aI1 = quad_sum(aI1); aG1 = quad_sum(aG1); aO1 = quad_sum(aO1);\
    float h0v, h1v;                                                                    \
    LSTM1(aF0, aI0, aG0, aO0, xv0, xv1, xv2, xv3, c0, h0v)                             \
    LSTM1(aF1, aI1, aG1, aO1, xw0, xw1, xw2, xw3, c1, h1v)                             \
    /* publish: each lane writes both units' bf16 into its own p-copy */               \
    ((unsigned short*)&hsh[HW][p][0])[v] = f2bf(h0v);                                  \
    ((unsigned short*)&hsh[HW][p][0])[v + 128] = f2bf(h1v);                            \
    if (p == 0) {                                                                      \
      __builtin_nontemporal_store(h0v, outp + ((size_t)t << 8) + v);                   \
      __builtin_nontemporal_store(h1v, outp + ((size_t)t << 8) + v + 128);             \
      if (t == 1023) {                                                                 \
        out[16777216 + b * 256 + v] = h0v;                                             \
        out[16777216 + b * 256 + v + 128] = h1v;                                       \
        out[16777216 + 16384 + b * 256 + v] = c0;                                      \
        out[16777216 + 16384 + b * 256 + v + 128] = c1;                                \
      }                                                                                \
    }                                                                                  \
    /* raw barrier: LDS ordering only -- no vmcnt drain of out-store/xp loads */       \
    BAR();                                                                             \
  }

  for (int t2 = 0; t2 < 1024; t2 += 2) {
    STEP(t2, 1, 0)      // t even: read h slot1, write slot0
    STEP(t2 + 1, 0, 1)  // t odd:  read h slot0, write slot1
  }
#undef STEP
#undef LSTM1
#undef HJC
#undef DOTC
#undef DOT2
#undef BAR
}

extern "C" void kernel_launch(void* const* d_in, const int* in_sizes, int n_in,
                              void* d_out, int out_size, void* d_ws, size_t ws_size,
                              hipStream_t stream) {
  (void)in_sizes; (void)n_in; (void)out_size;
  const float* x = (const float*)d_in[0];
  const float* W = (const float*)d_in[1];
  const float* bias = (const float*)d_in[2];
  float* out = (float*)d_out;
  char* ws = (char*)d_ws;

  unsigned int* Wx2 = (unsigned int*)ws;              // 524288 B
  unsigned int* Wh2 = (unsigned int*)(ws + 524288);   // 524288 B
  char* xpmem = ws + 1048576;

  const size_t need32 = 1048576 + (size_t)65536 * 1024 * 4;

  prep_wx<<<512, 256, 0, stream>>>(W, Wx2);
  prep_wh<<<512, 256, 0, stream>>>(W, Wh2);

  if (ws_size >= need32) {
    gemm_xp<float><<<dim3(8, 512), 256, 0, stream>>>(x, Wx2, bias, (float*)xpmem);
    lstm_rec<float><<<64, 512, 0, stream>>>(Wh2, (const float*)xpmem, out);
  } else {
    gemm_xp<unsigned short><<<dim3(8, 512), 256, 0, stream>>>(x, Wx2, bias,
                                                              (unsigned short*)xpmem);
    lstm_rec<unsigned short><<<64, 512, 0, stream>>>(Wh2, (const unsigned short*)xpmem, out);
  }
}